// Round 1
// baseline (670.422 us; speedup 1.0000x reference)
//
#include <hip/hip_runtime.h>

#define V_CNT 10475
#define J_CNT 55
#define NBETA 10
#define PF_DIM 486
#define NFRAMES 512
#define FT 8

__device__ __constant__ int c_parents[J_CNT] = {
    -1, 0, 0, 0, 1, 2, 3, 4, 5, 6, 7, 8, 9, 9, 9, 12, 13, 14, 16, 17, 18, 19,
    15, 15, 15,
    20, 25, 26, 20, 28, 29, 20, 31, 32, 20, 34, 35, 20, 37, 38,
    21, 40, 41, 21, 43, 44, 21, 46, 47, 21, 49, 50, 21, 52, 53};

// One block per frame (64 threads). Lanes 0..54 compute per-joint rotation
// matrices + shaped joints; lane 0 walks the kinematic chain in LDS.
__global__ __launch_bounds__(64) void skel_kernel(
    const float* __restrict__ body_pose, const float* __restrict__ betas,
    const float* __restrict__ global_orient, const float* __restrict__ J_template,
    const float* __restrict__ J_shapedirs, const float* __restrict__ odp,
    float* __restrict__ A_out, float* __restrict__ pf_out)
{
    const int n = blockIdx.x;
    const int lane = threadIdx.x;
    __shared__ float R_s[J_CNT][9];
    __shared__ float j_s[J_CNT][3];
    __shared__ float G_s[J_CNT][12];

    if (lane < J_CNT) {
        float aa0, aa1, aa2;
        if (lane == 0) {
            aa0 = global_orient[n * 3 + 0];
            aa1 = global_orient[n * 3 + 1];
            aa2 = global_orient[n * 3 + 2];
        } else if (lane < 22) {
            int o = n * 63 + (lane - 1) * 3;
            aa0 = body_pose[o]; aa1 = body_pose[o + 1]; aa2 = body_pose[o + 2];
        } else {
            int o = (lane - 22) * 3;
            aa0 = odp[o]; aa1 = odp[o + 1]; aa2 = odp[o + 2];
        }
        float ang = sqrtf(aa0 * aa0 + aa1 * aa1 + aa2 * aa2 + 1e-12f);
        float inv = 1.0f / ang;
        float ax = aa0 * inv, ay = aa1 * inv, az = aa2 * inv;
        float s = sinf(ang), c = cosf(ang), cc = 1.0f - c;
        float R[9];
        R[0] = c + cc * ax * ax;        R[1] = -s * az + cc * ax * ay;  R[2] = s * ay + cc * ax * az;
        R[3] = s * az + cc * ax * ay;   R[4] = c + cc * ay * ay;        R[5] = -s * ax + cc * ay * az;
        R[6] = -s * ay + cc * ax * az;  R[7] = s * ax + cc * ay * az;   R[8] = c + cc * az * az;
#pragma unroll
        for (int k = 0; k < 9; k++) R_s[lane][k] = R[k];
#pragma unroll
        for (int cd = 0; cd < 3; cd++) {
            float acc = J_template[lane * 3 + cd];
#pragma unroll
            for (int k = 0; k < NBETA; k++)
                acc += betas[n * NBETA + k] * J_shapedirs[(lane * 3 + cd) * NBETA + k];
            j_s[lane][cd] = acc;
        }
        if (lane >= 1) {
#pragma unroll
            for (int e = 0; e < 9; e++)
                pf_out[n * PF_DIM + (lane - 1) * 9 + e] =
                    R[e] - ((e == 0 || e == 4 || e == 8) ? 1.0f : 0.0f);
        }
    }
    __syncthreads();
    if (lane == 0) {
        for (int r = 0; r < 3; r++) {
            G_s[0][r * 4 + 0] = R_s[0][r * 3 + 0];
            G_s[0][r * 4 + 1] = R_s[0][r * 3 + 1];
            G_s[0][r * 4 + 2] = R_s[0][r * 3 + 2];
            G_s[0][r * 4 + 3] = j_s[0][r];
        }
        for (int i = 1; i < J_CNT; i++) {
            int p = c_parents[i];
            float rel0 = j_s[i][0] - j_s[p][0];
            float rel1 = j_s[i][1] - j_s[p][1];
            float rel2 = j_s[i][2] - j_s[p][2];
            for (int r = 0; r < 3; r++) {
                float g0 = G_s[p][r * 4 + 0], g1 = G_s[p][r * 4 + 1], g2 = G_s[p][r * 4 + 2];
                G_s[i][r * 4 + 0] = g0 * R_s[i][0] + g1 * R_s[i][3] + g2 * R_s[i][6];
                G_s[i][r * 4 + 1] = g0 * R_s[i][1] + g1 * R_s[i][4] + g2 * R_s[i][7];
                G_s[i][r * 4 + 2] = g0 * R_s[i][2] + g1 * R_s[i][5] + g2 * R_s[i][8];
                G_s[i][r * 4 + 3] = g0 * rel0 + g1 * rel1 + g2 * rel2 + G_s[p][r * 4 + 3];
            }
        }
    }
    __syncthreads();
    if (lane < J_CNT) {
        float* dst = &A_out[(n * J_CNT + lane) * 12];
        const float jx = j_s[lane][0], jy = j_s[lane][1], jz = j_s[lane][2];
#pragma unroll
        for (int r = 0; r < 3; r++) {
            float g0 = G_s[lane][r * 4 + 0], g1 = G_s[lane][r * 4 + 1], g2 = G_s[lane][r * 4 + 2];
            dst[r * 4 + 0] = g0;
            dst[r * 4 + 1] = g1;
            dst[r * 4 + 2] = g2;
            dst[r * 4 + 3] = G_s[lane][r * 4 + 3] - (g0 * jx + g1 * jy + g2 * jz);
        }
    }
}

// Vertex kernel: block = 256 vertices, FT=8 frames per block (grid.y tiles).
__global__ __launch_bounds__(256) void vert_kernel(
    const float* __restrict__ v_template, const float* __restrict__ shapedirs,
    const float* __restrict__ posedirs, const float* __restrict__ lbs_weights,
    const float* __restrict__ transl, const float* __restrict__ betas,
    const float* __restrict__ A_in, const float* __restrict__ pf_in,
    float* __restrict__ out)
{
    __shared__ float pf_s[FT * PF_DIM];      // 15.6 KB
    __shared__ float A_s[FT * J_CNT * 12];   // 21.1 KB
    __shared__ float tr_s[FT * 3];
    __shared__ float bet_s[FT * NBETA];

    const int tid = threadIdx.x;
    const int f0 = blockIdx.y * FT;

    for (int i = tid; i < FT * PF_DIM; i += 256) pf_s[i] = pf_in[f0 * PF_DIM + i];
    for (int i = tid; i < FT * J_CNT * 12; i += 256) A_s[i] = A_in[f0 * J_CNT * 12 + i];
    if (tid < FT * 3) tr_s[tid] = transl[f0 * 3 + tid];
    if (tid < FT * NBETA) bet_s[tid] = betas[f0 * NBETA + tid];
    __syncthreads();

    const int v = blockIdx.x * 256 + tid;
    if (v >= V_CNT) return;

    float sd[30];
#pragma unroll
    for (int i = 0; i < 30; i++) sd[i] = shapedirs[v * 30 + i];
    const float vt0 = v_template[v * 3 + 0];
    const float vt1 = v_template[v * 3 + 1];
    const float vt2 = v_template[v * 3 + 2];

    float vp[FT][3];
#pragma unroll
    for (int f = 0; f < FT; f++) {
        float a0 = vt0, a1 = vt1, a2 = vt2;
#pragma unroll
        for (int k = 0; k < NBETA; k++) {
            float b = bet_s[f * NBETA + k];
            a0 += b * sd[k];
            a1 += b * sd[10 + k];
            a2 += b * sd[20 + k];
        }
        vp[f][0] = a0; vp[f][1] = a1; vp[f][2] = a2;
    }

    const float* pdp = posedirs + (size_t)v * 3;
#pragma unroll 2
    for (int p = 0; p < PF_DIM; p++) {
        const float* q = pdp + (size_t)p * (V_CNT * 3);
        float d0 = q[0], d1 = q[1], d2 = q[2];
#pragma unroll
        for (int f = 0; f < FT; f++) {
            float w = pf_s[f * PF_DIM + p];
            vp[f][0] += w * d0;
            vp[f][1] += w * d1;
            vp[f][2] += w * d2;
        }
    }

    const float* lwp = lbs_weights + (size_t)v * J_CNT;
#pragma unroll 1
    for (int f = 0; f < FT; f++) {
        float T[12];
#pragma unroll
        for (int k = 0; k < 12; k++) T[k] = 0.0f;
        for (int j = 0; j < J_CNT; j++) {
            float w = lwp[j];
            const float* a = &A_s[(f * J_CNT + j) * 12];
#pragma unroll
            for (int k = 0; k < 12; k++) T[k] += w * a[k];
        }
        float x = vp[f][0], y = vp[f][1], z = vp[f][2];
        float o0 = T[0] * x + T[1] * y + T[2]  * z + T[3]  + tr_s[f * 3 + 0];
        float o1 = T[4] * x + T[5] * y + T[6]  * z + T[7]  + tr_s[f * 3 + 1];
        float o2 = T[8] * x + T[9] * y + T[10] * z + T[11] + tr_s[f * 3 + 2];
        size_t oi = ((size_t)(f0 + f) * V_CNT + v) * 3;
        out[oi + 0] = o0;
        out[oi + 1] = o1;
        out[oi + 2] = o2;
    }
}

extern "C" void kernel_launch(void* const* d_in, const int* in_sizes, int n_in,
                              void* d_out, int out_size, void* d_ws, size_t ws_size,
                              hipStream_t stream)
{
    const float* body_pose     = (const float*)d_in[0];
    const float* betas         = (const float*)d_in[1];
    const float* global_orient = (const float*)d_in[2];
    const float* transl        = (const float*)d_in[3];
    const float* v_template    = (const float*)d_in[4];
    const float* shapedirs     = (const float*)d_in[5];
    const float* posedirs      = (const float*)d_in[6];
    const float* lbs_weights   = (const float*)d_in[7];
    const float* J_template    = (const float*)d_in[8];
    const float* J_shapedirs   = (const float*)d_in[9];
    const float* odp           = (const float*)d_in[10];
    float* out = (float*)d_out;

    float* A_ws  = (float*)d_ws;                       // 512*55*12 floats
    float* pf_ws = A_ws + NFRAMES * J_CNT * 12;        // 512*486 floats

    skel_kernel<<<NFRAMES, 64, 0, stream>>>(body_pose, betas, global_orient,
                                            J_template, J_shapedirs, odp,
                                            A_ws, pf_ws);

    dim3 grid((V_CNT + 255) / 256, NFRAMES / FT);
    vert_kernel<<<grid, 256, 0, stream>>>(v_template, shapedirs, posedirs,
                                          lbs_weights, transl, betas,
                                          A_ws, pf_ws, out);
}

// Round 2
// 144.418 us; speedup vs baseline: 4.6422x; 4.6422x over previous
//
#include <hip/hip_runtime.h>

#define V_CNT   10475
#define N3      31425      // V*3
#define NPAD    31488      // 164*192
#define J_CNT   55
#define NBETA   10
#define KP      512        // padded K for GEMM1 (486 pf + 10 betas + 1 vt + pad)
#define NFRAMES 512
#define BM      64         // frames per block
#define BNC     192        // columns (verts*3) per block
#define VTILES  164
#define FTILES  8

typedef __attribute__((ext_vector_type(8))) __bf16 bf16x8;
typedef __attribute__((ext_vector_type(8))) unsigned short ushort8;
typedef __attribute__((ext_vector_type(4))) float f32x4;

__device__ __forceinline__ unsigned short f2bf(float f) {
    unsigned u = __float_as_uint(f);
    u += 0x7fff + ((u >> 16) & 1);
    return (unsigned short)(u >> 16);
}
__device__ __forceinline__ float bf2f(unsigned short s) {
    return __uint_as_float(((unsigned)s) << 16);
}
// global -> LDS direct 16B load. LDS dest must be wave-uniform; lane writes base+lane*16.
__device__ __forceinline__ void gl_lds16(const void* g, void* l) {
    auto gp = (const __attribute__((address_space(1))) unsigned int*)(uintptr_t)g;
    auto lp = (__attribute__((address_space(3))) unsigned int*)(unsigned int)(uintptr_t)l;
    __builtin_amdgcn_global_load_lds(gp, lp, 16, 0, 0);
}

__device__ __constant__ int c_parents[J_CNT] = {
    -1, 0, 0, 0, 1, 2, 3, 4, 5, 6, 7, 8, 9, 9, 9, 12, 13, 14, 16, 17, 18, 19,
    15, 15, 15,
    20, 25, 26, 20, 28, 29, 20, 31, 32, 20, 34, 35, 20, 37, 38,
    21, 40, 41, 21, 43, 44, 21, 46, 47, 21, 49, 50, 21, 52, 53};

// ---------------- skeleton: rotmats, kinematic chain, pf_ext(bf16), A_bf(bf16) ------------
__global__ __launch_bounds__(64) void skel_kernel(
    const float* __restrict__ body_pose, const float* __restrict__ betas,
    const float* __restrict__ global_orient, const float* __restrict__ J_template,
    const float* __restrict__ J_shapedirs, const float* __restrict__ odp,
    unsigned short* __restrict__ pf_ext, unsigned short* __restrict__ A_bf)
{
    const int n = blockIdx.x;
    const int lane = threadIdx.x;
    __shared__ float R_s[J_CNT][9];
    __shared__ float j_s[J_CNT][3];
    __shared__ float G_s[J_CNT][12];

    if (lane < J_CNT) {
        float aa0, aa1, aa2;
        if (lane == 0) {
            aa0 = global_orient[n * 3 + 0];
            aa1 = global_orient[n * 3 + 1];
            aa2 = global_orient[n * 3 + 2];
        } else if (lane < 22) {
            int o = n * 63 + (lane - 1) * 3;
            aa0 = body_pose[o]; aa1 = body_pose[o + 1]; aa2 = body_pose[o + 2];
        } else {
            int o = (lane - 22) * 3;
            aa0 = odp[o]; aa1 = odp[o + 1]; aa2 = odp[o + 2];
        }
        float ang = sqrtf(aa0 * aa0 + aa1 * aa1 + aa2 * aa2 + 1e-12f);
        float inv = 1.0f / ang;
        float ax = aa0 * inv, ay = aa1 * inv, az = aa2 * inv;
        float s = sinf(ang), c = cosf(ang), cc = 1.0f - c;
        float R[9];
        R[0] = c + cc * ax * ax;        R[1] = -s * az + cc * ax * ay;  R[2] = s * ay + cc * ax * az;
        R[3] = s * az + cc * ax * ay;   R[4] = c + cc * ay * ay;        R[5] = -s * ax + cc * ay * az;
        R[6] = -s * ay + cc * ax * az;  R[7] = s * ax + cc * ay * az;   R[8] = c + cc * az * az;
#pragma unroll
        for (int k = 0; k < 9; k++) R_s[lane][k] = R[k];
#pragma unroll
        for (int cd = 0; cd < 3; cd++) {
            float acc = J_template[lane * 3 + cd];
#pragma unroll
            for (int k = 0; k < NBETA; k++)
                acc += betas[n * NBETA + k] * J_shapedirs[(lane * 3 + cd) * NBETA + k];
            j_s[lane][cd] = acc;
        }
        if (lane >= 1) {
#pragma unroll
            for (int e = 0; e < 9; e++)
                pf_ext[n * KP + (lane - 1) * 9 + e] =
                    f2bf(R[e] - ((e == 0 || e == 4 || e == 8) ? 1.0f : 0.0f));
        }
    }
    if (lane == 55) {
#pragma unroll
        for (int b = 0; b < NBETA; b++) pf_ext[n * KP + 486 + b] = f2bf(betas[n * NBETA + b]);
        pf_ext[n * KP + 496] = 0x3F80;  // 1.0 bf16 (multiplies v_template row)
    }
    if (lane == 56) {
        for (int k = 497; k < KP; k++) pf_ext[n * KP + k] = 0;
    }
    __syncthreads();
    if (lane == 0) {
        for (int r = 0; r < 3; r++) {
            G_s[0][r * 4 + 0] = R_s[0][r * 3 + 0];
            G_s[0][r * 4 + 1] = R_s[0][r * 3 + 1];
            G_s[0][r * 4 + 2] = R_s[0][r * 3 + 2];
            G_s[0][r * 4 + 3] = j_s[0][r];
        }
        for (int i = 1; i < J_CNT; i++) {
            int p = c_parents[i];
            float rel0 = j_s[i][0] - j_s[p][0];
            float rel1 = j_s[i][1] - j_s[p][1];
            float rel2 = j_s[i][2] - j_s[p][2];
            for (int r = 0; r < 3; r++) {
                float g0 = G_s[p][r * 4 + 0], g1 = G_s[p][r * 4 + 1], g2 = G_s[p][r * 4 + 2];
                G_s[i][r * 4 + 0] = g0 * R_s[i][0] + g1 * R_s[i][3] + g2 * R_s[i][6];
                G_s[i][r * 4 + 1] = g0 * R_s[i][1] + g1 * R_s[i][4] + g2 * R_s[i][7];
                G_s[i][r * 4 + 2] = g0 * R_s[i][2] + g1 * R_s[i][5] + g2 * R_s[i][8];
                G_s[i][r * 4 + 3] = g0 * rel0 + g1 * rel1 + g2 * rel2 + G_s[p][r * 4 + 3];
            }
        }
    }
    __syncthreads();
    // A_bf[f][12][64]: row r = c*4+d of the 3x4 A matrix, K-dim = joint (padded to 64)
    float vals[12];
#pragma unroll
    for (int r = 0; r < 12; r++) vals[r] = 0.0f;
    if (lane < J_CNT) {
        const float jx = j_s[lane][0], jy = j_s[lane][1], jz = j_s[lane][2];
#pragma unroll
        for (int r = 0; r < 3; r++) {
            float g0 = G_s[lane][r * 4 + 0], g1 = G_s[lane][r * 4 + 1], g2 = G_s[lane][r * 4 + 2];
            vals[r * 4 + 0] = g0;
            vals[r * 4 + 1] = g1;
            vals[r * 4 + 2] = g2;
            vals[r * 4 + 3] = G_s[lane][r * 4 + 3] - (g0 * jx + g1 * jy + g2 * jz);
        }
    }
#pragma unroll
    for (int r = 0; r < 12; r++)
        A_bf[(n * 12 + r) * 64 + lane] = f2bf(vals[r]);
}

// ---------------- repack: B_pack[n][k] bf16 (transpose of posedirs, + shapedirs + v_template) ---
__global__ __launch_bounds__(256) void repack_kernel(
    const float* __restrict__ posedirs, const float* __restrict__ shapedirs,
    const float* __restrict__ v_template, unsigned short* __restrict__ B_pack)
{
    __shared__ float t[64][65];
    const int n0 = blockIdx.x * 64, k0 = blockIdx.y * 64;
    const int tn = threadIdx.x & 63, tk4 = threadIdx.x >> 6;
#pragma unroll
    for (int rep = 0; rep < 16; rep++) {
        int kl = rep * 4 + tk4;
        int kg = k0 + kl, ng = n0 + tn;
        float v = 0.0f;
        if (ng < N3) {
            if (kg < 486)       v = posedirs[(size_t)kg * N3 + ng];
            else if (kg < 496)  v = shapedirs[ng * NBETA + (kg - 486)];
            else if (kg == 496) v = v_template[ng];
        }
        t[kl][tn] = v;
    }
    __syncthreads();
#pragma unroll
    for (int rep = 0; rep < 16; rep++) {
        int nl = rep * 4 + tk4;
        B_pack[(size_t)(n0 + nl) * KP + k0 + tn] = f2bf(t[tn][nl]);
    }
}

// ---------------- fused GEMM: vposed (MFMA) -> skinning (MFMA) -> epilogue -----------------
// block: 64 frames x 64 verts (192 cols). 4 waves as 2x2; wave tile 32f x 96c.
__global__ __launch_bounds__(256, 2) void gemm_kernel(
    const unsigned short* __restrict__ pf_ext, const unsigned short* __restrict__ B_pack,
    const unsigned short* __restrict__ A_bf, const float* __restrict__ lbs_weights,
    const float* __restrict__ transl, float* __restrict__ out)
{
    // LDS carve: pf 8KB | B(24KB)/vp(24.5KB) union | w 8KB | transl 768B
    __shared__ __align__(128) unsigned char smem[42240];
    unsigned char* pf_b = smem;                // [64f][128B]  (64 k bf16/row, swizzled)
    unsigned char* B_b  = smem + 8192;         // [192n][128B] (swizzled)
    unsigned short* vp_s = (unsigned short*)(smem + 8192);   // [64f][196] bf16
    unsigned char* w_b  = smem + 8192 + 25088; // [64v][128B] = [64v][64j] bf16 swizzled
    float* tr_s = (float*)(smem + 8192 + 25088 + 8192);      // [64f][3]

    const int tid = threadIdx.x;
    const int w = tid >> 6, l = tid & 63;
    const int wm = w >> 1, wn = w & 1;         // wave tile: frames wm*32.., cols wn*96..
    const int f0 = blockIdx.y * BM;
    const int v00 = blockIdx.x * 64;
    const int n0c = blockIdx.x * BNC;

    // stage lbs weights tile -> w_b [64v][64j] bf16, XOR-swizzled chunks
    {
        int v = tid >> 2, jg = tid & 3;
        int vg = v00 + v;
#pragma unroll
        for (int h = 0; h < 2; h++) {
            ushort8 val;
#pragma unroll
            for (int e = 0; e < 8; e++) {
                int j = jg * 16 + h * 8 + e;
                float f = (vg < V_CNT && j < J_CNT) ? lbs_weights[vg * J_CNT + j] : 0.0f;
                val[e] = f2bf(f);
            }
            int chunk = (jg * 2 + h) ^ (v & 7);
            *(ushort8*)(w_b + v * 128 + chunk * 16) = val;
        }
    }
    if (tid < 192) tr_s[tid] = transl[f0 * 3 + tid];

    // -------- GEMM1: vp[f][n] = sum_k pf_ext[f][k] * B_pack[n][k] --------
    f32x4 acc[2][6];
#pragma unroll
    for (int m = 0; m < 2; m++)
#pragma unroll
        for (int nn = 0; nn < 6; nn++) acc[m][nn] = (f32x4){0.f, 0.f, 0.f, 0.f};

    const unsigned char* pfg = (const unsigned char*)pf_ext + (size_t)f0 * (KP * 2);
    const unsigned char* Bg  = (const unsigned char*)B_pack + (size_t)n0c * (KP * 2);

    for (int ks = 0; ks < 8; ks++) {
        __syncthreads();   // previous tile's ds_reads done
        const int kb = ks * 128;   // byte offset of this K-chunk within a 1KB row
        // pf: 64 rows x 128B ; 8 rows per wave-instruction, pre-swizzled source
#pragma unroll
        for (int i = 0; i < 2; i++) {
            int row0 = w * 16 + i * 8;
            int row = row0 + (l >> 3);
            const unsigned char* src = pfg + (size_t)row * (KP * 2) + kb + (((l & 7) ^ (l >> 3)) * 16);
            gl_lds16(src, pf_b + row0 * 128);
        }
        // B: 192 rows x 128B
#pragma unroll
        for (int i = 0; i < 6; i++) {
            int row0 = i * 32 + w * 8;
            int row = row0 + (l >> 3);
            const unsigned char* src = Bg + (size_t)row * (KP * 2) + kb + (((l & 7) ^ (l >> 3)) * 16);
            gl_lds16(src, B_b + row0 * 128);
        }
        __syncthreads();   // staging landed (each wave drains own vmcnt before barrier)
#pragma unroll
        for (int ksub = 0; ksub < 2; ksub++) {
            bf16x8 a[2], b[6];
#pragma unroll
            for (int m = 0; m < 2; m++) {
                int f = wm * 32 + m * 16 + (l & 15);
                int off = f * 128 + ((ksub * 64 + (l >> 4) * 16) ^ ((f & 7) << 4));
                a[m] = *(const bf16x8*)(pf_b + off);
            }
#pragma unroll
            for (int nn = 0; nn < 6; nn++) {
                int col = wn * 96 + nn * 16 + (l & 15);
                int off = col * 128 + ((ksub * 64 + (l >> 4) * 16) ^ ((col & 7) << 4));
                b[nn] = *(const bf16x8*)(B_b + off);
            }
#pragma unroll
            for (int m = 0; m < 2; m++)
#pragma unroll
                for (int nn = 0; nn < 6; nn++)
                    acc[m][nn] = __builtin_amdgcn_mfma_f32_16x16x32_bf16(a[m], b[nn], acc[m][nn], 0, 0, 0);
        }
    }

    __syncthreads();   // done reading B_b; vp_s overwrites it
    // write vp to LDS as bf16 [64f][196]
#pragma unroll
    for (int m = 0; m < 2; m++)
#pragma unroll
        for (int nn = 0; nn < 6; nn++)
#pragma unroll
            for (int e = 0; e < 4; e++) {
                int f = wm * 32 + m * 16 + (l >> 4) * 4 + e;
                int col = wn * 96 + nn * 16 + (l & 15);
                vp_s[f * 196 + col] = f2bf(acc[m][nn][e]);
            }
    __syncthreads();

    // -------- GEMM2 per coord c: T[f][v][c*4+rr] = sum_j A_bf[f][c*4+rr][j] * w[v][j] ------
    const unsigned char* Ab = (const unsigned char*)A_bf;
#pragma unroll 1
    for (int c = 0; c < 3; c++) {
        f32x4 acc2[8][2];
#pragma unroll
        for (int m = 0; m < 8; m++)
#pragma unroll
            for (int nn = 0; nn < 2; nn++) acc2[m][nn] = (f32x4){0.f, 0.f, 0.f, 0.f};
#pragma unroll
        for (int ksub = 0; ksub < 2; ksub++) {
            bf16x8 bw[2];
#pragma unroll
            for (int nn = 0; nn < 2; nn++) {
                int v = wn * 32 + nn * 16 + (l & 15);
                int off = v * 128 + ((ksub * 64 + (l >> 4) * 16) ^ ((v & 7) << 4));
                bw[nn] = *(const bf16x8*)(w_b + off);
            }
#pragma unroll
            for (int m = 0; m < 8; m++) {
                int row16 = l & 15;
                int f_rel = m * 4 + (row16 >> 2);
                int rr = row16 & 3;
                const unsigned char* asrc = Ab +
                    ((size_t)((f0 + wm * 32 + f_rel) * 12 + c * 4 + rr)) * 128 +
                    ksub * 64 + (l >> 4) * 16;
                bf16x8 af = *(const bf16x8*)asrc;
                acc2[m][0] = __builtin_amdgcn_mfma_f32_16x16x32_bf16(af, bw[0], acc2[m][0], 0, 0, 0);
                acc2[m][1] = __builtin_amdgcn_mfma_f32_16x16x32_bf16(af, bw[1], acc2[m][1], 0, 0, 0);
            }
        }
        // epilogue: out = T[0..2] . vp + T[3] + transl
#pragma unroll
        for (int m = 0; m < 8; m++)
#pragma unroll
            for (int nn = 0; nn < 2; nn++) {
                int f_rel = wm * 32 + m * 4 + (l >> 4);      // frame within block
                int vloc = wn * 32 + nn * 16 + (l & 15);     // vertex within block
                float d0 = bf2f(vp_s[f_rel * 196 + vloc * 3 + 0]);
                float d1 = bf2f(vp_s[f_rel * 196 + vloc * 3 + 1]);
                float d2 = bf2f(vp_s[f_rel * 196 + vloc * 3 + 2]);
                f32x4 tt = acc2[m][nn];
                float val = tt[0] * d0 + tt[1] * d1 + tt[2] * d2 + tt[3] + tr_s[f_rel * 3 + c];
                int vg = v00 + vloc;
                if (vg < V_CNT)
                    out[((size_t)(f0 + f_rel) * V_CNT + vg) * 3 + c] = val;
            }
    }
}

extern "C" void kernel_launch(void* const* d_in, const int* in_sizes, int n_in,
                              void* d_out, int out_size, void* d_ws, size_t ws_size,
                              hipStream_t stream)
{
    const float* body_pose     = (const float*)d_in[0];
    const float* betas         = (const float*)d_in[1];
    const float* global_orient = (const float*)d_in[2];
    const float* transl        = (const float*)d_in[3];
    const float* v_template    = (const float*)d_in[4];
    const float* shapedirs     = (const float*)d_in[5];
    const float* posedirs      = (const float*)d_in[6];
    const float* lbs_weights   = (const float*)d_in[7];
    const float* J_template    = (const float*)d_in[8];
    const float* J_shapedirs   = (const float*)d_in[9];
    const float* odp           = (const float*)d_in[10];
    float* out = (float*)d_out;

    // ws layout: B_pack 31488*512*2 = 32,243,712 | pf_ext 512*512*2 | A_bf 512*12*64*2
    unsigned short* B_pack = (unsigned short*)d_ws;
    unsigned short* pf_ext = (unsigned short*)((char*)d_ws + 32243712);
    unsigned short* A_bf   = (unsigned short*)((char*)d_ws + 32243712 + 524288);

    dim3 rgrid(NPAD / 64, KP / 64);
    repack_kernel<<<rgrid, 256, 0, stream>>>(posedirs, shapedirs, v_template, B_pack);

    skel_kernel<<<NFRAMES, 64, 0, stream>>>(body_pose, betas, global_orient,
                                            J_template, J_shapedirs, odp,
                                            pf_ext, A_bf);

    dim3 ggrid(VTILES, FTILES);
    gemm_kernel<<<ggrid, 256, 0, stream>>>(pf_ext, B_pack, A_bf, lbs_weights, transl, out);
}